// Round 8
// baseline (604.694 us; speedup 1.0000x reference)
//
#include <hip/hip_runtime.h>

// ---------------------------------------------------------------------------
// HedgeHog attention distillation map: pred = (fq.fk^T) rownorm, true = softmax(q0.k0^T/8)
// Output [2,2,16,2048,2048] fp32 = 1.07 GiB -> HBM-write-bound (~165us floor).
//
// v8: WAVE SPECIALIZATION. The vmcnt FIFO retires IN ORDER, so any wave that
// mixes loads and stores stalls its store stream on every operand-load wait
// (this is why v2..v7 all capped at ~2 TB/s while pure-store fill hits 6.5).
// Waves 0-3 (producers): global loads + MFMA + normalize + LDS write. NEVER store.
// Waves 4-7 (storers):   LDS read + 1KB global stores. NEVER load global, NEVER
// wait on vmcnt -> pure store stream like fillBufferAligned.
// Handshake: raw s_barrier pairs + lgkmcnt(0) (LDS only). 2 blocks/CU overlap.
// ---------------------------------------------------------------------------

typedef __attribute__((ext_vector_type(8))) short  bf16x8;
typedef __attribute__((ext_vector_type(4))) float  f32x4;

#define NN 2048
#define NBH 32

__device__ float g_part[NBH * 8 * 128];   // fk colsum partials

__device__ __forceinline__ float bf2f(unsigned short u) {
  union { unsigned int i; float f; } v; v.i = ((unsigned int)u) << 16; return v.f;
}
__device__ __forceinline__ unsigned short f2bf(float f) {
  union { float f; unsigned int i; } v; v.f = f;
  unsigned int x = v.i;
  return (unsigned short)((x + 0x7FFFu + ((x >> 16) & 1u)) >> 16);  // RNE
}
__device__ __forceinline__ bf16x8 cvt8(const float* __restrict__ p) {
  bf16x8 v;
#pragma unroll
  for (int i = 0; i < 8; i++) v[i] = (short)f2bf(p[i]);
  return v;
}
__device__ __forceinline__ f32x4 mfma16(bf16x8 a, bf16x8 b, f32x4 c) {
  return __builtin_amdgcn_mfma_f32_16x16x32_bf16(a, b, c, 0, 0, 0);
}

// ---------------------------------------------------------------------------
// Kernel 1: projections + hedgehog features. One wave owns 16 rows.
// ---------------------------------------------------------------------------
__device__ __forceinline__ void proj_chain(
    const bf16x8 ax[2],
    const float* __restrict__ W1, const float* __restrict__ b1,
    const float* __restrict__ W2, const float* __restrict__ b2,
    unsigned short* __restrict__ o1w, unsigned short* __restrict__ o2w,
    unsigned short (*Tq)[72], unsigned short (*Tf)[136],
    long r0, int l15, int g, int l)
{
#pragma unroll
  for (int nt = 0; nt < 4; nt++) {
    f32x4 acc = {0.f, 0.f, 0.f, 0.f};
    acc = mfma16(ax[0], cvt8(W1 + (nt * 16 + l15) * 64 + g * 8), acc);
    acc = mfma16(ax[1], cvt8(W1 + (nt * 16 + l15) * 64 + 32 + g * 8), acc);
    float bv = b1[nt * 16 + l15];
#pragma unroll
    for (int j = 0; j < 4; j++)
      Tq[g * 4 + j][nt * 16 + l15] = f2bf(acc[j] + bv);   // C layout: row=(l>>4)*4+j, col=l&15
  }
#pragma unroll
  for (int i = 0; i < 2; i++) {
    int c = i * 64 + l;
    int r = c >> 3, cc = c & 7;
    *(bf16x8*)(o1w + (r0 + r) * 64 + cc * 8) = *(const bf16x8*)&Tq[r][cc * 8];
  }
  bf16x8 a1[2];
#pragma unroll
  for (int kk = 0; kk < 2; kk++)
    a1[kk] = *(const bf16x8*)&Tq[l15][kk * 32 + g * 8];
#pragma unroll
  for (int nt = 0; nt < 4; nt++) {
    f32x4 acc = {0.f, 0.f, 0.f, 0.f};
    acc = mfma16(a1[0], cvt8(W2 + (nt * 16 + l15) * 64 + g * 8), acc);
    acc = mfma16(a1[1], cvt8(W2 + (nt * 16 + l15) * 64 + 32 + g * 8), acc);
    float bv = b2[nt * 16 + l15];
#pragma unroll
    for (int j = 0; j < 4; j++) {
      float h = acc[j] + bv;
      Tf[g * 4 + j][nt * 16 + l15]      = f2bf(__expf(h));
      Tf[g * 4 + j][64 + nt * 16 + l15] = f2bf(__expf(-h));
    }
  }
#pragma unroll
  for (int i = 0; i < 4; i++) {
    int c = i * 64 + l;
    int r = c >> 4, cc = c & 15;
    *(bf16x8*)(o2w + (r0 + r) * 128 + cc * 8) = *(const bf16x8*)&Tf[r][cc * 8];
  }
}

__global__ __launch_bounds__(256) void k_proj(
    const float* __restrict__ x,
    const float* __restrict__ Wq,  const float* __restrict__ bq,
    const float* __restrict__ Wk,  const float* __restrict__ bk,
    const float* __restrict__ Wmq, const float* __restrict__ bmq,
    const float* __restrict__ Wmk, const float* __restrict__ bmk,
    unsigned short* __restrict__ q0w, unsigned short* __restrict__ k0w,
    unsigned short* __restrict__ fqw, unsigned short* __restrict__ fkw)
{
  const int tid = threadIdx.x;
  const int w = tid >> 6, l = tid & 63;
  const int l15 = l & 15, g = l >> 4;
  const long r0 = ((long)blockIdx.x * 4 + w) * 16;

  __shared__ unsigned short TqS[4][16][72];
  __shared__ unsigned short TfS[4][16][136];

  bf16x8 ax[2];
#pragma unroll
  for (int kk = 0; kk < 2; kk++)
    ax[kk] = cvt8(x + (r0 + l15) * 64 + kk * 32 + g * 8);

  proj_chain(ax, Wq, bq, Wmq, bmq, q0w, fqw, TqS[w], TfS[w], r0, l15, g, l);
  proj_chain(ax, Wk, bk, Wmk, bmk, k0w, fkw, TqS[w], TfS[w], r0, l15, g, l);
}

// ---------------------------------------------------------------------------
// Kernel 2: fk column-sum partials (bh, part): rows part*256..+255.
// ---------------------------------------------------------------------------
__global__ __launch_bounds__(256) void k_colsum1(const unsigned short* __restrict__ fkw)
{
  const int bh = blockIdx.x, part = blockIdx.y;
  const int tid = threadIdx.x;
  const int cg = tid & 15, rg = tid >> 4;
  const unsigned short* fkp = fkw + ((long)bh * NN + part * 256 + rg * 16) * 128 + cg * 8;

  float a8[8] = {0.f, 0.f, 0.f, 0.f, 0.f, 0.f, 0.f, 0.f};
#pragma unroll
  for (int r = 0; r < 16; r++) {
    bf16x8 v = *(const bf16x8*)(fkp + (long)r * 128);
#pragma unroll
    for (int j = 0; j < 8; j++) a8[j] += bf2f((unsigned short)v[j]);
  }
  __shared__ float red[16][132];
#pragma unroll
  for (int j = 0; j < 8; j++) red[rg][cg * 8 + j] = a8[j];
  __syncthreads();
  if (tid < 128) {
    float s = 0.f;
#pragma unroll
    for (int r = 0; r < 16; r++) s += red[r][tid];
    g_part[(bh * 8 + part) * 128 + tid] = s;
  }
}

// ---------------------------------------------------------------------------
// Kernel 3: producer/consumer strip writer. Block = (bh, 16 q-rows), 8 waves.
// 8 chunks of 16x512 fp32 (4 pred + 4 true). Producers (w0-3) fill LDS;
// storers (w4-7) stream 1KB bursts, never touching vmcnt waits.
// ---------------------------------------------------------------------------
__global__ __launch_bounds__(512, 4) void k_write(
    const unsigned short* __restrict__ q0w, const unsigned short* __restrict__ k0w,
    const unsigned short* __restrict__ fqw, const unsigned short* __restrict__ fkw,
    float* __restrict__ out)
{
  const int bh = blockIdx.x;          // 0..31
  const int rq = blockIdx.y;          // 0..127
  const int tid = threadIdx.x;
  const int w = tid >> 6, l = tid & 63;
  const int l15 = l & 15, g = l >> 4;
  const int rqe = (rq + bh * 37) & 127;
  const int qrow0 = rqe * 16;

  __shared__ float buf[16][516];      // 32KB chunk (+pad)
  __shared__ float sred[4][16];

  const unsigned short* fqp = fqw + ((long)bh * NN + qrow0) * 128;
  const unsigned short* q0p = q0w + ((long)bh * NN + qrow0) * 64;
  const unsigned short* fkp = fkw + (long)bh * NN * 128;
  const unsigned short* k0p = k0w + (long)bh * NN * 64;
  const long ob_p = (long)bh * NN * NN + (long)qrow0 * NN;
  const long ob_t = ob_p + (long)NBH * NN * NN;

  bf16x8 afq[4], aq0[2];
  float ip[4] = {0.f, 0.f, 0.f, 0.f};
  float it[4] = {0.f, 0.f, 0.f, 0.f};

  if (w < 4) {
    // ---- A fragments ----
#pragma unroll
    for (int kk = 0; kk < 4; kk++)
      afq[kk] = *(const bf16x8*)(fqp + l15 * 128 + kk * 32 + g * 8);
#pragma unroll
    for (int kk = 0; kk < 2; kk++)
      aq0[kk] = *(const bf16x8*)(q0p + l15 * 64 + kk * 32 + g * 8);

    // ---- pred reciprocals: ip = 1 / (fq[row] . Sfk) ----
    float dotv = 0.f;
    {
      const unsigned short* p = fqp + (long)l15 * 128 + g * 32;
      const float* pp = g_part + bh * 1024 + g * 32;
#pragma unroll
      for (int i = 0; i < 32; i += 8) {
        bf16x8 v = *(const bf16x8*)(p + i);
#pragma unroll
        for (int jj = 0; jj < 8; jj++) {
          float s = 0.f;
#pragma unroll
          for (int pt = 0; pt < 8; pt++) s += pp[pt * 128 + i + jj];
          dotv += bf2f((unsigned short)v[jj]) * s;
        }
      }
    }
    dotv += __shfl_xor(dotv, 16, 64);
    dotv += __shfl_xor(dotv, 32, 64);
#pragma unroll
    for (int j = 0; j < 4; j++)
      ip[j] = 1.0f / __shfl(dotv, (g * 4 + j) & 15, 16);

    // ---- true row sums (tiles split across 4 producer waves) ----
    float st[4] = {0.f, 0.f, 0.f, 0.f};
    for (int t = w; t < 128; t += 4) {
      const unsigned short* bp = k0p + (long)(t * 16 + l15) * 64 + g * 8;
      f32x4 acc = {0.f, 0.f, 0.f, 0.f};
      acc = mfma16(aq0[0], *(const bf16x8*)bp, acc);
      acc = mfma16(aq0[1], *(const bf16x8*)(bp + 32), acc);
#pragma unroll
      for (int j = 0; j < 4; j++) st[j] += __expf(acc[j] * 0.125f);
    }
#pragma unroll
    for (int j = 0; j < 4; j++) {
      float v = st[j];
      v += __shfl_xor(v, 1, 16);
      v += __shfl_xor(v, 2, 16);
      v += __shfl_xor(v, 4, 16);
      v += __shfl_xor(v, 8, 16);
      if (l15 == 0) sred[w][g * 4 + j] = v;
    }
  }
  __syncthreads();
  if (w < 4) {
#pragma unroll
    for (int j = 0; j < 4; j++)
      it[j] = 1.0f / (sred[0][g * 4 + j] + sred[1][g * 4 + j] +
                      sred[2][g * 4 + j] + sred[3][g * 4 + j]);
  }

  // ---- 8 chunks: 4 pred quarters then 4 true quarters ----
  for (int c = 0; c < 8; c++) {
    const int plane = c >> 2, qd = c & 3;
    if (w < 4) {
      // ================= producer =================
      if (plane == 0) {
#pragma unroll 4
        for (int tt = 0; tt < 8; tt++) {
          const int colc = w * 128 + tt * 16;             // 0..511 within chunk
          const unsigned short* bp = fkp + (long)(qd * 512 + colc + l15) * 128 + g * 8;
          f32x4 acc = {0.f, 0.f, 0.f, 0.f};
#pragma unroll
          for (int kk = 0; kk < 4; kk++)
            acc = mfma16(afq[kk], *(const bf16x8*)(bp + kk * 32), acc);
#pragma unroll
          for (int j = 0; j < 4; j++)
            buf[g * 4 + j][colc + l15] = acc[j] * ip[j];
        }
      } else {
#pragma unroll 4
        for (int tt = 0; tt < 8; tt++) {
          const int colc = w * 128 + tt * 16;
          const unsigned short* bp = k0p + (long)(qd * 512 + colc + l15) * 64 + g * 8;
          f32x4 acc = {0.f, 0.f, 0.f, 0.f};
          acc = mfma16(aq0[0], *(const bf16x8*)bp, acc);
          acc = mfma16(aq0[1], *(const bf16x8*)(bp + 32), acc);
#pragma unroll
          for (int j = 0; j < 4; j++)
            buf[g * 4 + j][colc + l15] = __expf(acc[j] * 0.125f) * it[j];
        }
      }
      asm volatile("s_waitcnt lgkmcnt(0)" ::: "memory");
      __builtin_amdgcn_s_barrier();                 // data ready
      __builtin_amdgcn_sched_barrier(0);
      __builtin_amdgcn_s_barrier();                 // data consumed
      __builtin_amdgcn_sched_barrier(0);
    } else {
      // ================= storer =================
      __builtin_amdgcn_s_barrier();                 // data ready
      __builtin_amdgcn_sched_barrier(0);
      const int sw = w - 4;
      const long ob = (plane ? ob_t : ob_p) + qd * 512;
#pragma unroll
      for (int r = 0; r < 4; r++) {
        const int row = sw * 4 + r;
#pragma unroll
        for (int s = 0; s < 2; s++) {
          f32x4 v = *(const f32x4*)&buf[row][s * 256 + l * 4];
          *(f32x4*)(out + ob + (long)row * NN + s * 256 + l * 4) = v;
        }
      }
      asm volatile("s_waitcnt lgkmcnt(0)" ::: "memory");
      __builtin_amdgcn_s_barrier();                 // data consumed
      __builtin_amdgcn_sched_barrier(0);
    }
  }
}

extern "C" void kernel_launch(void* const* d_in, const int* in_sizes, int n_in,
                              void* d_out, int out_size, void* d_ws, size_t ws_size,
                              hipStream_t stream) {
  const float* x   = (const float*)d_in[0];
  const float* Wq  = (const float*)d_in[1];
  const float* bq  = (const float*)d_in[2];
  const float* Wk  = (const float*)d_in[3];
  const float* bk  = (const float*)d_in[4];
  const float* Wmq = (const float*)d_in[5];
  const float* bmq = (const float*)d_in[6];
  const float* Wmk = (const float*)d_in[7];
  const float* bmk = (const float*)d_in[8];
  float* out = (float*)d_out;

  // ws layout (bf16): q0[32][2048][64], k0[...], fq[32][2048][128], fk[...] = 48 MB
  unsigned short* q0w = (unsigned short*)d_ws;
  unsigned short* k0w = q0w + (long)NBH * NN * 64;
  unsigned short* fqw = k0w + (long)NBH * NN * 64;
  unsigned short* fkw = fqw + (long)NBH * NN * 128;

  hipLaunchKernelGGL(k_proj, dim3(1024), dim3(256), 0, stream,
                     x, Wq, bq, Wk, bk, Wmq, bmq, Wmk, bmk, q0w, k0w, fqw, fkw);
  hipLaunchKernelGGL(k_colsum1, dim3(NBH, 8), dim3(256), 0, stream, fkw);
  hipLaunchKernelGGL(k_write, dim3(NBH, 128), dim3(512), 0, stream,
                     q0w, k0w, fqw, fkw, out);
}

// Round 9
// 601.345 us; speedup vs baseline: 1.0056x; 1.0056x over previous
//
#include <hip/hip_runtime.h>

// ---------------------------------------------------------------------------
// HedgeHog attention distillation map: pred = (fq.fk^T) rownorm, true = softmax(q0.k0^T/8)
// Output [2,2,16,2048,2048] fp32 = 1.07 GiB -> HBM-write-bound (~165us floor).
//
// v9: wave specialization + DOUBLE-BUFFERED LDS = stores flow during compute.
// v8's single buffer serialized produce->store per block (chip-wide store duty
// ~35% -> 2 TB/s). Now: storers stream chunk c from buf[c&1] WHILE producers
// fill buf[(c+1)&1]; one raw s_barrier per iteration. Producer vmcnt FIFO:
// loads only. Storer FIFO: stores only, never waited on. Plain stores (nt
// amplified WRITE by 20% in v6).
// ---------------------------------------------------------------------------

typedef __attribute__((ext_vector_type(8))) short  bf16x8;
typedef __attribute__((ext_vector_type(4))) float  f32x4;

#define NN 2048
#define NBH 32

__device__ float g_part[NBH * 8 * 128];   // fk colsum partials

__device__ __forceinline__ float bf2f(unsigned short u) {
  union { unsigned int i; float f; } v; v.i = ((unsigned int)u) << 16; return v.f;
}
__device__ __forceinline__ unsigned short f2bf(float f) {
  union { float f; unsigned int i; } v; v.f = f;
  unsigned int x = v.i;
  return (unsigned short)((x + 0x7FFFu + ((x >> 16) & 1u)) >> 16);  // RNE
}
__device__ __forceinline__ bf16x8 cvt8(const float* __restrict__ p) {
  bf16x8 v;
#pragma unroll
  for (int i = 0; i < 8; i++) v[i] = (short)f2bf(p[i]);
  return v;
}
__device__ __forceinline__ f32x4 mfma16(bf16x8 a, bf16x8 b, f32x4 c) {
  return __builtin_amdgcn_mfma_f32_16x16x32_bf16(a, b, c, 0, 0, 0);
}

// ---------------------------------------------------------------------------
// Kernel 1: projections + hedgehog features. One wave owns 16 rows.
// ---------------------------------------------------------------------------
__device__ __forceinline__ void proj_chain(
    const bf16x8 ax[2],
    const float* __restrict__ W1, const float* __restrict__ b1,
    const float* __restrict__ W2, const float* __restrict__ b2,
    unsigned short* __restrict__ o1w, unsigned short* __restrict__ o2w,
    unsigned short (*Tq)[72], unsigned short (*Tf)[136],
    long r0, int l15, int g, int l)
{
#pragma unroll
  for (int nt = 0; nt < 4; nt++) {
    f32x4 acc = {0.f, 0.f, 0.f, 0.f};
    acc = mfma16(ax[0], cvt8(W1 + (nt * 16 + l15) * 64 + g * 8), acc);
    acc = mfma16(ax[1], cvt8(W1 + (nt * 16 + l15) * 64 + 32 + g * 8), acc);
    float bv = b1[nt * 16 + l15];
#pragma unroll
    for (int j = 0; j < 4; j++)
      Tq[g * 4 + j][nt * 16 + l15] = f2bf(acc[j] + bv);   // C layout: row=(l>>4)*4+j, col=l&15
  }
#pragma unroll
  for (int i = 0; i < 2; i++) {
    int c = i * 64 + l;
    int r = c >> 3, cc = c & 7;
    *(bf16x8*)(o1w + (r0 + r) * 64 + cc * 8) = *(const bf16x8*)&Tq[r][cc * 8];
  }
  bf16x8 a1[2];
#pragma unroll
  for (int kk = 0; kk < 2; kk++)
    a1[kk] = *(const bf16x8*)&Tq[l15][kk * 32 + g * 8];
#pragma unroll
  for (int nt = 0; nt < 4; nt++) {
    f32x4 acc = {0.f, 0.f, 0.f, 0.f};
    acc = mfma16(a1[0], cvt8(W2 + (nt * 16 + l15) * 64 + g * 8), acc);
    acc = mfma16(a1[1], cvt8(W2 + (nt * 16 + l15) * 64 + 32 + g * 8), acc);
    float bv = b2[nt * 16 + l15];
#pragma unroll
    for (int j = 0; j < 4; j++) {
      float h = acc[j] + bv;
      Tf[g * 4 + j][nt * 16 + l15]      = f2bf(__expf(h));
      Tf[g * 4 + j][64 + nt * 16 + l15] = f2bf(__expf(-h));
    }
  }
#pragma unroll
  for (int i = 0; i < 4; i++) {
    int c = i * 64 + l;
    int r = c >> 4, cc = c & 15;
    *(bf16x8*)(o2w + (r0 + r) * 128 + cc * 8) = *(const bf16x8*)&Tf[r][cc * 8];
  }
}

__global__ __launch_bounds__(256) void k_proj(
    const float* __restrict__ x,
    const float* __restrict__ Wq,  const float* __restrict__ bq,
    const float* __restrict__ Wk,  const float* __restrict__ bk,
    const float* __restrict__ Wmq, const float* __restrict__ bmq,
    const float* __restrict__ Wmk, const float* __restrict__ bmk,
    unsigned short* __restrict__ q0w, unsigned short* __restrict__ k0w,
    unsigned short* __restrict__ fqw, unsigned short* __restrict__ fkw)
{
  const int tid = threadIdx.x;
  const int w = tid >> 6, l = tid & 63;
  const int l15 = l & 15, g = l >> 4;
  const long r0 = ((long)blockIdx.x * 4 + w) * 16;

  __shared__ unsigned short TqS[4][16][72];
  __shared__ unsigned short TfS[4][16][136];

  bf16x8 ax[2];
#pragma unroll
  for (int kk = 0; kk < 2; kk++)
    ax[kk] = cvt8(x + (r0 + l15) * 64 + kk * 32 + g * 8);

  proj_chain(ax, Wq, bq, Wmq, bmq, q0w, fqw, TqS[w], TfS[w], r0, l15, g, l);
  proj_chain(ax, Wk, bk, Wmk, bmk, k0w, fkw, TqS[w], TfS[w], r0, l15, g, l);
}

// ---------------------------------------------------------------------------
// Kernel 2: fk column-sum partials (bh, part): rows part*256..+255.
// ---------------------------------------------------------------------------
__global__ __launch_bounds__(256) void k_colsum1(const unsigned short* __restrict__ fkw)
{
  const int bh = blockIdx.x, part = blockIdx.y;
  const int tid = threadIdx.x;
  const int cg = tid & 15, rg = tid >> 4;
  const unsigned short* fkp = fkw + ((long)bh * NN + part * 256 + rg * 16) * 128 + cg * 8;

  float a8[8] = {0.f, 0.f, 0.f, 0.f, 0.f, 0.f, 0.f, 0.f};
#pragma unroll
  for (int r = 0; r < 16; r++) {
    bf16x8 v = *(const bf16x8*)(fkp + (long)r * 128);
#pragma unroll
    for (int j = 0; j < 8; j++) a8[j] += bf2f((unsigned short)v[j]);
  }
  __shared__ float red[16][132];
#pragma unroll
  for (int j = 0; j < 8; j++) red[rg][cg * 8 + j] = a8[j];
  __syncthreads();
  if (tid < 128) {
    float s = 0.f;
#pragma unroll
    for (int r = 0; r < 16; r++) s += red[r][tid];
    g_part[(bh * 8 + part) * 128 + tid] = s;
  }
}

// ---------------------------------------------------------------------------
// Kernel 3: producer/consumer with double-buffered LDS. Block = (bh,16 rows),
// 8 waves. 16 chunks of 16x256 fp32 (8 pred + 8 true). Storers stream chunk c
// while producers fill chunk c+1. One raw s_barrier per iteration.
// ---------------------------------------------------------------------------
__global__ __launch_bounds__(512, 4) void k_write(
    const unsigned short* __restrict__ q0w, const unsigned short* __restrict__ k0w,
    const unsigned short* __restrict__ fqw, const unsigned short* __restrict__ fkw,
    float* __restrict__ out)
{
  const int bh = blockIdx.x;          // 0..31
  const int rq = blockIdx.y;          // 0..127
  const int tid = threadIdx.x;
  const int w = tid >> 6, l = tid & 63;
  const int l15 = l & 15, g = l >> 4;
  const int rqe = (rq + bh * 37) & 127;
  const int qrow0 = rqe * 16;

  __shared__ float buf[2][16][260];   // double-buffered 16x256 chunk (33KB)
  __shared__ float sred[8][16];

  const unsigned short* fqp = fqw + ((long)bh * NN + qrow0) * 128;
  const unsigned short* q0p = q0w + ((long)bh * NN + qrow0) * 64;
  const unsigned short* fkp = fkw + (long)bh * NN * 128;
  const unsigned short* k0p = k0w + (long)bh * NN * 64;
  const long ob_p = (long)bh * NN * NN + (long)qrow0 * NN;
  const long ob_t = ob_p + (long)NBH * NN * NN;

  // ---- A fragments (needed by all waves for the shared sum prologue) ----
  bf16x8 aq0[2];
#pragma unroll
  for (int kk = 0; kk < 2; kk++)
    aq0[kk] = *(const bf16x8*)(q0p + l15 * 64 + kk * 32 + g * 8);

  // ---- true row sums: full k0 scan split across ALL 8 waves ----
  {
    float st[4] = {0.f, 0.f, 0.f, 0.f};
    for (int t = w; t < 128; t += 8) {
      const unsigned short* bp = k0p + (long)(t * 16 + l15) * 64 + g * 8;
      f32x4 acc = {0.f, 0.f, 0.f, 0.f};
      acc = mfma16(aq0[0], *(const bf16x8*)bp, acc);
      acc = mfma16(aq0[1], *(const bf16x8*)(bp + 32), acc);
#pragma unroll
      for (int j = 0; j < 4; j++) st[j] += __expf(acc[j] * 0.125f);
    }
#pragma unroll
    for (int j = 0; j < 4; j++) {
      float v = st[j];
      v += __shfl_xor(v, 1, 16);
      v += __shfl_xor(v, 2, 16);
      v += __shfl_xor(v, 4, 16);
      v += __shfl_xor(v, 8, 16);
      if (l15 == 0) sred[w][g * 4 + j] = v;
    }
  }
  __syncthreads();   // drains prologue loads for storers too (vmcnt(0) here is fine)

  bf16x8 afq[4];
  float ip[4] = {0.f, 0.f, 0.f, 0.f};
  float it[4] = {0.f, 0.f, 0.f, 0.f};

  if (w < 4) {
    // producers: fq fragments + normalizers
#pragma unroll
    for (int kk = 0; kk < 4; kk++)
      afq[kk] = *(const bf16x8*)(fqp + l15 * 128 + kk * 32 + g * 8);

#pragma unroll
    for (int j = 0; j < 4; j++) {
      float s = 0.f;
#pragma unroll
      for (int ww = 0; ww < 8; ww++) s += sred[ww][g * 4 + j];
      it[j] = 1.0f / s;
    }

    float dotv = 0.f;
    {
      const unsigned short* p = fqp + (long)l15 * 128 + g * 32;
      const float* pp = g_part + bh * 1024 + g * 32;
#pragma unroll
      for (int i = 0; i < 32; i += 8) {
        bf16x8 v = *(const bf16x8*)(p + i);
#pragma unroll
        for (int jj = 0; jj < 8; jj++) {
          float s = 0.f;
#pragma unroll
          for (int pt = 0; pt < 8; pt++) s += pp[pt * 128 + i + jj];
          dotv += bf2f((unsigned short)v[jj]) * s;
        }
      }
    }
    dotv += __shfl_xor(dotv, 16, 64);
    dotv += __shfl_xor(dotv, 32, 64);
#pragma unroll
    for (int j = 0; j < 4; j++)
      ip[j] = 1.0f / __shfl(dotv, (g * 4 + j) & 15, 16);
  }

  // ---- produce chunk `c` into buf[c&1]: 4 col-tiles per producer wave ----
#define PRODUCE(C) {                                                           \
    const int pl_ = (C) >> 3, qd_ = (C) & 7;                                   \
    float (*b_)[260] = buf[(C) & 1];                                           \
    if (pl_ == 0) {                                                            \
      _Pragma("unroll")                                                        \
      for (int tt = 0; tt < 4; tt++) {                                         \
        const int col_ = w * 64 + tt * 16;                                     \
        const unsigned short* bp_ = fkp + (long)(qd_ * 256 + col_ + l15) * 128 + g * 8; \
        f32x4 acc_ = {0.f, 0.f, 0.f, 0.f};                                     \
        _Pragma("unroll")                                                      \
        for (int kk = 0; kk < 4; kk++)                                         \
          acc_ = mfma16(afq[kk], *(const bf16x8*)(bp_ + kk * 32), acc_);       \
        _Pragma("unroll")                                                      \
        for (int j_ = 0; j_ < 4; j_++)                                         \
          b_[g * 4 + j_][col_ + l15] = acc_[j_] * ip[j_];                      \
      }                                                                        \
    } else {                                                                   \
      _Pragma("unroll")                                                        \
      for (int tt = 0; tt < 4; tt++) {                                         \
        const int col_ = w * 64 + tt * 16;                                     \
        const unsigned short* bp_ = k0p + (long)(qd_ * 256 + col_ + l15) * 64 + g * 8; \
        f32x4 acc_ = {0.f, 0.f, 0.f, 0.f};                                     \
        acc_ = mfma16(aq0[0], *(const bf16x8*)bp_, acc_);                      \
        acc_ = mfma16(aq0[1], *(const bf16x8*)(bp_ + 32), acc_);               \
        _Pragma("unroll")                                                      \
        for (int j_ = 0; j_ < 4; j_++)                                         \
          b_[g * 4 + j_][col_ + l15] = __expf(acc_[j_] * 0.125f) * it[j_];     \
      }                                                                        \
    }                                                                          \
  }

  if (w < 4) {
    PRODUCE(0);
    asm volatile("s_waitcnt lgkmcnt(0)" ::: "memory");
    __builtin_amdgcn_s_barrier();                 // chunk 0 ready
    __builtin_amdgcn_sched_barrier(0);
    for (int c = 0; c < 16; c++) {
      if (c < 15) PRODUCE(c + 1);
      asm volatile("s_waitcnt lgkmcnt(0)" ::: "memory");
      __builtin_amdgcn_s_barrier();               // c+1 ready AND c consumed
      __builtin_amdgcn_sched_barrier(0);
    }
  } else {
    const int sw = w - 4;
    __builtin_amdgcn_s_barrier();                 // chunk 0 ready
    __builtin_amdgcn_sched_barrier(0);
    for (int c = 0; c < 16; c++) {
      const int pl = c >> 3, qd = c & 7;
      const long ob = (pl ? ob_t : ob_p) + qd * 256;
      float (*b_)[260] = buf[c & 1];
#pragma unroll
      for (int r = 0; r < 4; r++) {
        const int row = sw * 4 + r;
        f32x4 v = *(const f32x4*)&b_[row][l * 4];
        *(f32x4*)(out + ob + (long)row * NN + l * 4) = v;   // store issues only after ds_read done
      }
      __builtin_amdgcn_s_barrier();               // c consumed (ds_reads complete: stores issued)
      __builtin_amdgcn_sched_barrier(0);
    }
  }
}
#undef PRODUCE

extern "C" void kernel_launch(void* const* d_in, const int* in_sizes, int n_in,
                              void* d_out, int out_size, void* d_ws, size_t ws_size,
                              hipStream_t stream) {
  const float* x   = (const float*)d_in[0];
  const float* Wq  = (const float*)d_in[1];
  const float* bq  = (const float*)d_in[2];
  const float* Wk  = (const float*)d_in[3];
  const float* bk  = (const float*)d_in[4];
  const float* Wmq = (const float*)d_in[5];
  const float* bmq = (const float*)d_in[6];
  const float* Wmk = (const float*)d_in[7];
  const float* bmk = (const float*)d_in[8];
  float* out = (float*)d_out;

  // ws layout (bf16): q0[32][2048][64], k0[...], fq[32][2048][128], fk[...] = 48 MB
  unsigned short* q0w = (unsigned short*)d_ws;
  unsigned short* k0w = q0w + (long)NBH * NN * 64;
  unsigned short* fqw = k0w + (long)NBH * NN * 64;
  unsigned short* fkw = fqw + (long)NBH * NN * 128;

  hipLaunchKernelGGL(k_proj, dim3(1024), dim3(256), 0, stream,
                     x, Wq, bq, Wk, bk, Wmq, bmq, Wmk, bmk, q0w, k0w, fqw, fkw);
  hipLaunchKernelGGL(k_colsum1, dim3(NBH, 8), dim3(256), 0, stream, fkw);
  hipLaunchKernelGGL(k_write, dim3(NBH, 128), dim3(512), 0, stream,
                     q0w, k0w, fqw, fkw, out);
}

// Round 10
// 574.879 us; speedup vs baseline: 1.0519x; 1.0460x over previous
//
#include <hip/hip_runtime.h>

// ---------------------------------------------------------------------------
// HedgeHog attention distillation map: pred = (fq.fk^T) rownorm, true = softmax(q0.k0^T/8)
// Output [2,2,16,2048,2048] fp32 = 1.07 GiB -> HBM-write-bound (~165us floor).
//
// v10: kill producer load latency. v9 data: ~9600 cy per chunk vs ~600 nominal
// -> producers latency-bound on operand loads (inflated by the write stream),
// storer cadence slaved to producers via barrier. Fixes:
//  - k_norm: precompute ALL row normalizers once (g_normP/g_normT); k_write
//    blocks start streaming instantly, true-plane MFMA work halves.
//  - k_write: producers register-prefetch operands ONE FULL CHUNK ahead
//    (counted vmcnt(8), never blocking on a just-issued load); ring-4 LDS
//    out-buffer, storers 2 chunks behind; storers remain pure-store.
// ---------------------------------------------------------------------------

typedef __attribute__((ext_vector_type(8))) short  bf16x8;
typedef __attribute__((ext_vector_type(4))) float  f32x4;

#define NN 2048
#define NBH 32

__device__ float g_part[NBH * 8 * 128];   // fk colsum partials
__device__ float g_normP[NBH * NN];       // 1 / pred row sum
__device__ float g_normT[NBH * NN];       // 1 / true row sum

__device__ __forceinline__ float bf2f(unsigned short u) {
  union { unsigned int i; float f; } v; v.i = ((unsigned int)u) << 16; return v.f;
}
__device__ __forceinline__ unsigned short f2bf(float f) {
  union { float f; unsigned int i; } v; v.f = f;
  unsigned int x = v.i;
  return (unsigned short)((x + 0x7FFFu + ((x >> 16) & 1u)) >> 16);  // RNE
}
__device__ __forceinline__ bf16x8 cvt8(const float* __restrict__ p) {
  bf16x8 v;
#pragma unroll
  for (int i = 0; i < 8; i++) v[i] = (short)f2bf(p[i]);
  return v;
}
__device__ __forceinline__ f32x4 mfma16(bf16x8 a, bf16x8 b, f32x4 c) {
  return __builtin_amdgcn_mfma_f32_16x16x32_bf16(a, b, c, 0, 0, 0);
}

// ---------------------------------------------------------------------------
// Kernel 1: projections + hedgehog features. One wave owns 16 rows.
// ---------------------------------------------------------------------------
__device__ __forceinline__ void proj_chain(
    const bf16x8 ax[2],
    const float* __restrict__ W1, const float* __restrict__ b1,
    const float* __restrict__ W2, const float* __restrict__ b2,
    unsigned short* __restrict__ o1w, unsigned short* __restrict__ o2w,
    unsigned short (*Tq)[72], unsigned short (*Tf)[136],
    long r0, int l15, int g, int l)
{
#pragma unroll
  for (int nt = 0; nt < 4; nt++) {
    f32x4 acc = {0.f, 0.f, 0.f, 0.f};
    acc = mfma16(ax[0], cvt8(W1 + (nt * 16 + l15) * 64 + g * 8), acc);
    acc = mfma16(ax[1], cvt8(W1 + (nt * 16 + l15) * 64 + 32 + g * 8), acc);
    float bv = b1[nt * 16 + l15];
#pragma unroll
    for (int j = 0; j < 4; j++)
      Tq[g * 4 + j][nt * 16 + l15] = f2bf(acc[j] + bv);   // C layout: row=(l>>4)*4+j, col=l&15
  }
#pragma unroll
  for (int i = 0; i < 2; i++) {
    int c = i * 64 + l;
    int r = c >> 3, cc = c & 7;
    *(bf16x8*)(o1w + (r0 + r) * 64 + cc * 8) = *(const bf16x8*)&Tq[r][cc * 8];
  }
  bf16x8 a1[2];
#pragma unroll
  for (int kk = 0; kk < 2; kk++)
    a1[kk] = *(const bf16x8*)&Tq[l15][kk * 32 + g * 8];
#pragma unroll
  for (int nt = 0; nt < 4; nt++) {
    f32x4 acc = {0.f, 0.f, 0.f, 0.f};
    acc = mfma16(a1[0], cvt8(W2 + (nt * 16 + l15) * 64 + g * 8), acc);
    acc = mfma16(a1[1], cvt8(W2 + (nt * 16 + l15) * 64 + 32 + g * 8), acc);
    float bv = b2[nt * 16 + l15];
#pragma unroll
    for (int j = 0; j < 4; j++) {
      float h = acc[j] + bv;
      Tf[g * 4 + j][nt * 16 + l15]      = f2bf(__expf(h));
      Tf[g * 4 + j][64 + nt * 16 + l15] = f2bf(__expf(-h));
    }
  }
#pragma unroll
  for (int i = 0; i < 4; i++) {
    int c = i * 64 + l;
    int r = c >> 4, cc = c & 15;
    *(bf16x8*)(o2w + (r0 + r) * 128 + cc * 8) = *(const bf16x8*)&Tf[r][cc * 8];
  }
}

__global__ __launch_bounds__(256) void k_proj(
    const float* __restrict__ x,
    const float* __restrict__ Wq,  const float* __restrict__ bq,
    const float* __restrict__ Wk,  const float* __restrict__ bk,
    const float* __restrict__ Wmq, const float* __restrict__ bmq,
    const float* __restrict__ Wmk, const float* __restrict__ bmk,
    unsigned short* __restrict__ q0w, unsigned short* __restrict__ k0w,
    unsigned short* __restrict__ fqw, unsigned short* __restrict__ fkw)
{
  const int tid = threadIdx.x;
  const int w = tid >> 6, l = tid & 63;
  const int l15 = l & 15, g = l >> 4;
  const long r0 = ((long)blockIdx.x * 4 + w) * 16;

  __shared__ unsigned short TqS[4][16][72];
  __shared__ unsigned short TfS[4][16][136];

  bf16x8 ax[2];
#pragma unroll
  for (int kk = 0; kk < 2; kk++)
    ax[kk] = cvt8(x + (r0 + l15) * 64 + kk * 32 + g * 8);

  proj_chain(ax, Wq, bq, Wmq, bmq, q0w, fqw, TqS[w], TfS[w], r0, l15, g, l);
  proj_chain(ax, Wk, bk, Wmk, bmk, k0w, fkw, TqS[w], TfS[w], r0, l15, g, l);
}

// ---------------------------------------------------------------------------
// Kernel 2: fk column-sum partials (bh, part): rows part*256..+255.
// ---------------------------------------------------------------------------
__global__ __launch_bounds__(256) void k_colsum1(const unsigned short* __restrict__ fkw)
{
  const int bh = blockIdx.x, part = blockIdx.y;
  const int tid = threadIdx.x;
  const int cg = tid & 15, rg = tid >> 4;
  const unsigned short* fkp = fkw + ((long)bh * NN + part * 256 + rg * 16) * 128 + cg * 8;

  float a8[8] = {0.f, 0.f, 0.f, 0.f, 0.f, 0.f, 0.f, 0.f};
#pragma unroll
  for (int r = 0; r < 16; r++) {
    bf16x8 v = *(const bf16x8*)(fkp + (long)r * 128);
#pragma unroll
    for (int j = 0; j < 8; j++) a8[j] += bf2f((unsigned short)v[j]);
  }
  __shared__ float red[16][132];
#pragma unroll
  for (int j = 0; j < 8; j++) red[rg][cg * 8 + j] = a8[j];
  __syncthreads();
  if (tid < 128) {
    float s = 0.f;
#pragma unroll
    for (int r = 0; r < 16; r++) s += red[r][tid];
    g_part[(bh * 8 + part) * 128 + tid] = s;
  }
}

// ---------------------------------------------------------------------------
// Kernel 3: row normalizers. Block = (bh, 128-row group), 4 waves.
// pred: 1/(fq[row].Sfk). true: 1/sum_n exp(q0.k0/8) via full MFMA scan.
// ---------------------------------------------------------------------------
__global__ __launch_bounds__(256) void k_norm(
    const unsigned short* __restrict__ q0w, const unsigned short* __restrict__ k0w,
    const unsigned short* __restrict__ fqw)
{
  const int bh = blockIdx.x, rg = blockIdx.y;
  const int tid = threadIdx.x;
  const int w = tid >> 6, l = tid & 63;
  const int l15 = l & 15, g = l >> 4;

  __shared__ float sfk[128];
  if (tid < 128) {
    float s = 0.f;
#pragma unroll
    for (int pt = 0; pt < 8; pt++) s += g_part[bh * 1024 + pt * 128 + tid];
    sfk[tid] = s;
  }
  __syncthreads();
  if (tid < 128) {
    const int row = rg * 128 + tid;
    const unsigned short* p = fqw + ((long)bh * NN + row) * 128;
    float d = 0.f;
#pragma unroll
    for (int i = 0; i < 16; i++) {
      bf16x8 v = *(const bf16x8*)(p + i * 8);
#pragma unroll
      for (int jj = 0; jj < 8; jj++) d += bf2f((unsigned short)v[jj]) * sfk[i * 8 + jj];
    }
    g_normP[bh * NN + row] = 1.0f / d;
  }

  const unsigned short* k0p = k0w + (long)bh * NN * 64;
#pragma unroll
  for (int tt = 0; tt < 2; tt++) {
    const int rb = rg * 128 + w * 32 + tt * 16;
    const unsigned short* qp = q0w + ((long)bh * NN + rb) * 64;
    bf16x8 a0 = *(const bf16x8*)(qp + l15 * 64 + g * 8);
    bf16x8 a1 = *(const bf16x8*)(qp + l15 * 64 + 32 + g * 8);
    float st[4] = {0.f, 0.f, 0.f, 0.f};
    for (int kt = 0; kt < 128; kt++) {
      const unsigned short* bp = k0p + (long)(kt * 16 + l15) * 64 + g * 8;
      f32x4 acc = {0.f, 0.f, 0.f, 0.f};
      acc = mfma16(a0, *(const bf16x8*)bp, acc);
      acc = mfma16(a1, *(const bf16x8*)(bp + 32), acc);
#pragma unroll
      for (int j = 0; j < 4; j++) st[j] += __expf(acc[j] * 0.125f);
    }
#pragma unroll
    for (int j = 0; j < 4; j++) {
      float v = st[j];
      v += __shfl_xor(v, 1, 16);
      v += __shfl_xor(v, 2, 16);
      v += __shfl_xor(v, 4, 16);
      v += __shfl_xor(v, 8, 16);
      if (l15 == 0) g_normT[bh * NN + rb + g * 4 + j] = 1.0f / v;
    }
  }
}

// ---------------------------------------------------------------------------
// Kernel 4: pipelined producer/consumer writer. Block = (bh, 16 rows), 8 waves.
// 32 chunks of 16x128 fp32 (16 pred + 16 true). Producers (w0-3): prefetch
// chunk c+1's operands to regs, MFMA chunk c (counted vmcnt), scale, ds_write
// ring slot c&3. Storers (w4-7): 2 chunks behind, ds_read + 512B-run stores,
// never a global load. One raw s_barrier per chunk.
// ---------------------------------------------------------------------------
#define CHUNKS 32

#define PREF(CN, BK) {                                                        \
  if ((CN) < CHUNKS) {                                                        \
    const int pl_ = (CN) >> 4, kc_ = ((CN) & 15) * 128;                       \
    if (pl_ == 0) {                                                           \
      _Pragma("unroll")                                                       \
      for (int tt_ = 0; tt_ < 2; tt_++) {                                     \
        const unsigned short* bp_ = fkp + (long)(kc_ + w * 32 + tt_ * 16 + l15) * 128 + g * 8; \
        _Pragma("unroll")                                                     \
        for (int kk_ = 0; kk_ < 4; kk_++)                                     \
          BK[tt_ * 4 + kk_] = *(const bf16x8*)(bp_ + kk_ * 32);               \
      }                                                                       \
    } else {                                                                  \
      _Pragma("unroll")                                                       \
      for (int tt_ = 0; tt_ < 2; tt_++) {                                     \
        const unsigned short* bp_ = k0p + (long)(kc_ + w * 32 + tt_ * 16 + l15) * 64 + g * 8; \
        _Pragma("unroll")                                                     \
        for (int kk_ = 0; kk_ < 2; kk_++)                                     \
          BK[tt_ * 4 + kk_] = *(const bf16x8*)(bp_ + kk_ * 32);               \
      }                                                                       \
    }                                                                         \
  }                                                                           \
}

#define COMPUTE(C, BK) {                                                      \
  const int pl_ = (C) >> 4;                                                   \
  float (*b_)[132] = obuf[(C) & 3];                                           \
  if (pl_ == 0) {                                                             \
    _Pragma("unroll")                                                         \
    for (int tt_ = 0; tt_ < 2; tt_++) {                                       \
      f32x4 acc_ = {0.f, 0.f, 0.f, 0.f};                                      \
      _Pragma("unroll")                                                       \
      for (int kk_ = 0; kk_ < 4; kk_++)                                       \
        acc_ = mfma16(afq[kk_], BK[tt_ * 4 + kk_], acc_);                     \
      _Pragma("unroll")                                                       \
      for (int j_ = 0; j_ < 4; j_++)                                          \
        b_[g * 4 + j_][w * 32 + tt_ * 16 + l15] = acc_[j_] * ip[j_];          \
    }                                                                         \
  } else {                                                                    \
    _Pragma("unroll")                                                         \
    for (int tt_ = 0; tt_ < 2; tt_++) {                                       \
      f32x4 acc_ = {0.f, 0.f, 0.f, 0.f};                                      \
      acc_ = mfma16(aq0[0], BK[tt_ * 4 + 0], acc_);                           \
      acc_ = mfma16(aq0[1], BK[tt_ * 4 + 1], acc_);                           \
      _Pragma("unroll")                                                       \
      for (int j_ = 0; j_ < 4; j_++)                                          \
        b_[g * 4 + j_][w * 32 + tt_ * 16 + l15] = __expf(acc_[j_] * 0.125f) * it[j_]; \
    }                                                                         \
  }                                                                           \
}

#define STORE(S) {                                                            \
  const int pl_ = (S) >> 4, kc_ = ((S) & 15) * 128;                           \
  const long ob_ = (pl_ ? ob_t : ob_p) + kc_;                                 \
  float (*b_)[132] = obuf[(S) & 3];                                           \
  _Pragma("unroll")                                                           \
  for (int i_ = 0; i_ < 2; i_++) {                                            \
    const int row_ = sw * 4 + i_ * 2 + (l >> 5);                              \
    f32x4 v_ = *(const f32x4*)&b_[row_][(l & 31) * 4];                        \
    *(f32x4*)(out + ob_ + (long)row_ * NN + (l & 31) * 4) = v_;               \
  }                                                                           \
}

#define WITER(IT, CUR, NXT) {                                                 \
  if (w < 4) {                                                                \
    if ((IT) < CHUNKS) {                                                      \
      PREF((IT) + 1, NXT);                                                    \
      COMPUTE((IT), CUR);                                                     \
      asm volatile("s_waitcnt lgkmcnt(0)" ::: "memory");                      \
    }                                                                         \
  } else {                                                                    \
    if ((IT) >= 2) STORE((IT) - 2);                                           \
  }                                                                           \
  __builtin_amdgcn_s_barrier();                                               \
  __builtin_amdgcn_sched_barrier(0);                                          \
}

__global__ __launch_bounds__(512, 4) void k_write(
    const unsigned short* __restrict__ q0w, const unsigned short* __restrict__ k0w,
    const unsigned short* __restrict__ fqw, const unsigned short* __restrict__ fkw,
    float* __restrict__ out)
{
  const int bh = blockIdx.x;          // 0..31
  const int rq = blockIdx.y;          // 0..127
  const int tid = threadIdx.x;
  const int w = tid >> 6, l = tid & 63;
  const int l15 = l & 15, g = l >> 4;
  const int sw = w - 4;
  const int qrow0 = rq * 16;

  __shared__ float obuf[4][16][132];  // ring-4 16x128 chunk (34KB)

  const unsigned short* fkp = fkw + (long)bh * NN * 128;
  const unsigned short* k0p = k0w + (long)bh * NN * 64;
  const long ob_p = (long)bh * NN * NN + (long)qrow0 * NN;
  const long ob_t = ob_p + (long)NBH * NN * NN;

  bf16x8 afq[4], aq0[2], pa[8], pb[8];
  float ip[4], it[4];

  if (w < 4) {
    const unsigned short* fqp = fqw + ((long)bh * NN + qrow0) * 128;
    const unsigned short* q0p = q0w + ((long)bh * NN + qrow0) * 64;
#pragma unroll
    for (int kk = 0; kk < 4; kk++)
      afq[kk] = *(const bf16x8*)(fqp + l15 * 128 + kk * 32 + g * 8);
#pragma unroll
    for (int kk = 0; kk < 2; kk++)
      aq0[kk] = *(const bf16x8*)(q0p + l15 * 64 + kk * 32 + g * 8);
#pragma unroll
    for (int j = 0; j < 4; j++) {
      ip[j] = g_normP[bh * NN + qrow0 + g * 4 + j];
      it[j] = g_normT[bh * NN + qrow0 + g * 4 + j];
    }
    PREF(0, pa);
  }

#pragma unroll 1
  for (int p2 = 0; p2 < 17; p2++) {   // 34 iterations: 32 chunks + 2 drain
    const int it0 = p2 * 2;
    WITER(it0, pa, pb);
    WITER(it0 + 1, pb, pa);
  }
}

extern "C" void kernel_launch(void* const* d_in, const int* in_sizes, int n_in,
                              void* d_out, int out_size, void* d_ws, size_t ws_size,
                              hipStream_t stream) {
  const float* x   = (const float*)d_in[0];
  const float* Wq  = (const float*)d_in[1];
  const float* bq  = (const float*)d_in[2];
  const float* Wk  = (const float*)d_in[3];
  const float* bk  = (const float*)d_in[4];
  const float* Wmq = (const float*)d_in[5];
  const float* bmq = (const float*)d_in[6];
  const float* Wmk = (const float*)d_in[7];
  const float* bmk = (const float*)d_in[8];
  float* out = (float*)d_out;

  // ws layout (bf16): q0[32][2048][64], k0[...], fq[32][2048][128], fk[...] = 48 MB
  unsigned short* q0w = (unsigned short*)d_ws;
  unsigned short* k0w = q0w + (long)NBH * NN * 64;
  unsigned short* fqw = k0w + (long)NBH * NN * 64;
  unsigned short* fkw = fqw + (long)NBH * NN * 128;

  hipLaunchKernelGGL(k_proj, dim3(1024), dim3(256), 0, stream,
                     x, Wq, bq, Wk, bk, Wmq, bmq, Wmk, bmk, q0w, k0w, fqw, fkw);
  hipLaunchKernelGGL(k_colsum1, dim3(NBH, 8), dim3(256), 0, stream, fkw);
  hipLaunchKernelGGL(k_norm, dim3(NBH, 16), dim3(256), 0, stream, q0w, k0w, fqw);
  hipLaunchKernelGGL(k_write, dim3(NBH, 128), dim3(512), 0, stream,
                     q0w, k0w, fqw, fkw, out);
}